// Round 9
// baseline (937.803 us; speedup 1.0000x reference)
//
#include <hip/hip_runtime.h>

#define B_ 256
#define T_ 1024
#define E_ 32
#define H_ 128
#define NOBS_ 1048576
#define L2E 1.4426950408889634f
#define CLM 30.0f

#define HROW 144              // bytes per h row in LDS (128 i8 + 16 pad)
#define HBUF (4 * HROW)       // one group's h buffer (4 rows)

typedef __attribute__((ext_vector_type(8))) short bf16x8;
typedef __attribute__((ext_vector_type(4))) float f32x4;
typedef __attribute__((ext_vector_type(4))) int   i32x4;

// LDS-only barrier: drains LDS ops only; global loads/stores stay in flight.
#define LDS_BARRIER() asm volatile("s_waitcnt lgkmcnt(0)\n\ts_barrier" ::: "memory")

__device__ __forceinline__ short f2bf(float x) {
    unsigned u = __float_as_uint(x);
    unsigned r = u + 0x7FFFu + ((u >> 16) & 1u);   // RNE
    return (short)(r >> 16);
}

__device__ __forceinline__ bf16x8 pack8(float4 lo, float4 hi) {
    int x0, x1, x2, x3;
    asm("v_cvt_pk_bf16_f32 %0, %1, %2" : "=v"(x0) : "v"(lo.x), "v"(lo.y));
    asm("v_cvt_pk_bf16_f32 %0, %1, %2" : "=v"(x1) : "v"(lo.z), "v"(lo.w));
    asm("v_cvt_pk_bf16_f32 %0, %1, %2" : "=v"(x2) : "v"(hi.x), "v"(hi.y));
    asm("v_cvt_pk_bf16_f32 %0, %1, %2" : "=v"(x3) : "v"(hi.z), "v"(hi.w));
    i32x4 xi; xi[0] = x0; xi[1] = x1; xi[2] = x2; xi[3] = x3;
    return __builtin_bit_cast(bf16x8, xi);
}

// ---------------- embedding kernel (R7, proven) ----------------
__global__ void embed_kernel(const int* __restrict__ obs_ids,
                             const int* __restrict__ obs_slot,
                             const int* __restrict__ action_ids,
                             const int* __restrict__ is_action,
                             const float* __restrict__ action_emb,
                             const float* __restrict__ obs_emb,
                             float* __restrict__ embedded,
                             unsigned short* __restrict__ xbf) {
    __shared__ float s_act[5 * E_];
    __shared__ float s_obs[11 * E_];
    for (int i = threadIdx.x; i < 5 * E_; i += blockDim.x) s_act[i] = action_emb[i];
    for (int i = threadIdx.x; i < 11 * E_; i += blockDim.x) s_obs[i] = obs_emb[i];
    __syncthreads();

    int s = blockIdx.x * blockDim.x + threadIdx.x;
    if (s >= B_ * T_) return;

    float acc[E_];
    if (is_action[s]) {
        int a = action_ids[s];
        #pragma unroll
        for (int e = 0; e < E_; e++) acc[e] = s_act[a * E_ + e];
    } else {
        #pragma unroll
        for (int e = 0; e < E_; e++) acc[e] = 0.0f;
        int lo = 0, hi = NOBS_;
        while (lo < hi) {
            int mid = (lo + hi) >> 1;
            if (obs_slot[mid] < s) lo = mid + 1; else hi = mid;
        }
        int j = lo;
        while (j < NOBS_ && obs_slot[j] == s) {
            int id = obs_ids[j];
            #pragma unroll
            for (int e = 0; e < E_; e++) acc[e] += s_obs[id * E_ + e];
            j++;
        }
    }
    float4* dst = (float4*)(embedded + (size_t)s * E_);
    #pragma unroll
    for (int q = 0; q < E_ / 4; q++) {
        float4 v; v.x = acc[4*q]; v.y = acc[4*q+1]; v.z = acc[4*q+2]; v.w = acc[4*q+3];
        dst[q] = v;
    }
    if (xbf) {
        unsigned short tmp[E_];
        #pragma unroll
        for (int e = 0; e < E_; e++) tmp[e] = (unsigned short)f2bf(acc[e]);
        int4* d2 = (int4*)(xbf + (size_t)s * E_);
        #pragma unroll
        for (int q = 0; q < E_ / 8; q++) d2[q] = ((const int4*)tmp)[q];
    }
}

// ---------------- anti-phased LSTM, in-kernel x-MFMA (R7 numerics) ----------------
// 32 blocks x 8 rows = two independent 4-row groups A (rows 0-3), B (rows 4-7).
// Phase1: read A h-frags, x-MFMA(A,t) + i8 h-MFMA(A,t) issue to matrix pipe
// while the VALU runs EW_B(t-1); barrier. Phase2: symmetric. All MFMA layouts
// are the x4-duplicated-A-row patterns proven in R4-R7; no pre-GEMM.
__launch_bounds__(512, 2)
__global__ void lstm_ap2_kernel(const unsigned short* __restrict__ xbf,
                                const int* __restrict__ lengths,
                                const float* __restrict__ W_ih,
                                const float* __restrict__ W_hh,
                                const float* __restrict__ b_ih,
                                const float* __restrict__ b_hh,
                                float* __restrict__ outputs,
                                float* __restrict__ h_out,
                                float* __restrict__ c_out) {
    __shared__ __align__(16) char ldsA[HBUF];
    __shared__ __align__(16) char ldsB[HBUF];

    const int tid  = threadIdx.x;
    const int lane = tid & 63;
    const int wave = tid >> 6;
    const int row0 = blockIdx.x * 8;

    const int col16  = (wave << 4) + (lane & 15);
    const int kgrp8  = (lane >> 4) * 8;
    const int kgrp16 = (lane >> 4) * 16;
    const int brow   = (lane & 15) >> 2;
    const int g_own  = lane >> 4;

    // ---- weights: x-part bf16 (scaled by log2e; 2x for g), h-part i8 ----
    bf16x8 wx[4]; f32x4 biasv[4]; i32x4 wh[4][2]; float dq[4];
    #pragma unroll
    for (int gt = 0; gt < 4; gt++) {
        const float scale = (gt == 2) ? (2.0f * L2E) : L2E;
        const int gcol = gt * H_ + col16;
        {
            const float* p = W_ih + (size_t)gcol * E_ + kgrp8;
            bf16x8 v;
            #pragma unroll
            for (int j = 0; j < 8; j++) v[j] = f2bf(p[j] * scale);
            wx[gt] = v;
        }
        biasv[gt] = (f32x4)((b_ih[gcol] + b_hh[gcol]) * scale);
        const float* q = W_hh + (size_t)gcol * H_;
        float m = 0.0f;
        #pragma unroll
        for (int t2 = 0; t2 < 2; t2++)
            #pragma unroll
            for (int j = 0; j < 16; j++)
                m = fmaxf(m, fabsf(q[t2 * 64 + kgrp16 + j]));
        m = fmaxf(m, __shfl_xor(m, 16));
        m = fmaxf(m, __shfl_xor(m, 32));
        const float s = 127.0f / m;
        dq[gt] = scale * m * (1.0f / (127.0f * 127.0f));
        #pragma unroll
        for (int t2 = 0; t2 < 2; t2++) {
            i32x4 v;
            #pragma unroll
            for (int d = 0; d < 4; d++) {
                int word = 0;
                #pragma unroll
                for (int b2 = 0; b2 < 4; b2++) {
                    int qi = (int)rintf(q[t2 * 64 + kgrp16 + d * 4 + b2] * s);
                    word |= (qi & 0xFF) << (b2 * 8);
                }
                v[d] = word;
            }
            wh[gt][t2] = v;
        }
    }

    const int lenA = lengths[row0 + g_own];
    const int lenB = lengths[row0 + 4 + g_own];
    float cA = 0.f, hA = 0.f, cB = 0.f, hB = 0.f;

    const int rbase = brow * HROW + kgrp16;
    const int wofs  = g_own * HROW + col16;

    const unsigned short* xpA = xbf + ((size_t)(row0 + brow) * T_) * E_ + kgrp8;
    const unsigned short* xpB = xbf + ((size_t)(row0 + 4 + brow) * T_) * E_ + kgrp8;
    float* const outA = outputs + (size_t)(row0 + g_own) * T_ * H_ + col16;
    float* const outB = outputs + (size_t)(row0 + 4 + g_own) * T_ * H_ + col16;

    for (int i = tid; i < HBUF; i += 512) { ldsA[i] = 0; ldsB[i] = 0; }
    __syncthreads();

    int4 xA = *(const int4*)xpA;      // x_A(0)
    int4 xB = *(const int4*)xpB;      // x_B(0)

    i32x4 accA[4] = {}, accB[4] = {};
    f32x4 accfA[4] = {}, accfB[4] = {};

    // elementwise: shared-rcp, clamps at 30 (verified algebra)
    auto EW = [&](const i32x4* acc, const f32x4* accf, int t, int len,
                  float& cr, float& hr, float* outp, char* ldsw) {
        float a_i = fmaf((float)acc[0][0], dq[0], accf[0][0]);
        float a_f = fmaf((float)acc[1][0], dq[1], accf[1][0]);
        float a_g = fmaf((float)acc[2][0], dq[2], accf[2][0]);
        float a_o = fmaf((float)acc[3][0], dq[3], accf[3][0]);
        float Ai = exp2f(fminf(-a_i, CLM));
        float Af = exp2f(fminf(-a_f, CLM));
        float Eg = exp2f(fminf(a_g, CLM));
        float pAi = 1.0f + Ai, pAf = 1.0f + Af, pEg = Eg + 1.0f;
        float D  = pAi * pEg;
        float R  = __builtin_amdgcn_rcpf(D * pAf);
        float f_ = D * R;                         // sigmoid(a_f)
        float ig = (Eg - 1.0f) * pAf * R;         // sigmoid(a_i)*tanh(g)
        float c_new = fmaf(f_, cr, ig);
        float Ec = exp2f(fminf(c_new * (2.0f * L2E), CLM));
        float Ao = exp2f(fminf(-a_o, CLM));
        float Rh = __builtin_amdgcn_rcpf((1.0f + Ao) * (Ec + 1.0f));
        float h_new = (Ec - 1.0f) * Rh;           // sigmoid(a_o)*tanh(c)
        bool m = (t < len);
        cr = m ? c_new : cr;
        hr = m ? h_new : hr;
        outp[(size_t)t * H_] = m ? h_new : 0.0f;  // fire-and-forget
        int qh = (int)rintf(hr * 127.0f);
        ldsw[wofs] = (char)qh;
    };

    for (int i = 0; i < T_; ++i) {
        // ---- phase 1: A x+h MFMA(i) || EW_B(i-1) ----
        i32x4 a0 = *(const i32x4*)&ldsA[rbase];
        i32x4 a1 = *(const i32x4*)&ldsA[rbase + 64];
        bf16x8 xaA = __builtin_bit_cast(bf16x8, xA);
        if (i + 1 < T_) xA = *(const int4*)(xpA + (size_t)(i + 1) * E_);
        #pragma unroll
        for (int gt = 0; gt < 4; gt++)
            accfA[gt] = __builtin_amdgcn_mfma_f32_16x16x32_bf16(xaA, wx[gt], biasv[gt], 0, 0, 0);
        #pragma unroll
        for (int gt = 0; gt < 4; gt++)
            accA[gt] = __builtin_amdgcn_mfma_i32_16x16x64_i8(a0, wh[gt][0], (i32x4)0, 0, 0, 0);
        #pragma unroll
        for (int gt = 0; gt < 4; gt++)
            accA[gt] = __builtin_amdgcn_mfma_i32_16x16x64_i8(a1, wh[gt][1], accA[gt], 0, 0, 0);
        if (i > 0) EW(accB, accfB, i - 1, lenB, cB, hB, outB, ldsB);
        LDS_BARRIER();

        // ---- phase 2: B x+h MFMA(i) || EW_A(i) ----
        i32x4 b0 = *(const i32x4*)&ldsB[rbase];
        i32x4 b1 = *(const i32x4*)&ldsB[rbase + 64];
        bf16x8 xaB = __builtin_bit_cast(bf16x8, xB);
        if (i + 1 < T_) xB = *(const int4*)(xpB + (size_t)(i + 1) * E_);
        #pragma unroll
        for (int gt = 0; gt < 4; gt++)
            accfB[gt] = __builtin_amdgcn_mfma_f32_16x16x32_bf16(xaB, wx[gt], biasv[gt], 0, 0, 0);
        #pragma unroll
        for (int gt = 0; gt < 4; gt++)
            accB[gt] = __builtin_amdgcn_mfma_i32_16x16x64_i8(b0, wh[gt][0], (i32x4)0, 0, 0, 0);
        #pragma unroll
        for (int gt = 0; gt < 4; gt++)
            accB[gt] = __builtin_amdgcn_mfma_i32_16x16x64_i8(b1, wh[gt][1], accB[gt], 0, 0, 0);
        EW(accA, accfA, i, lenA, cA, hA, outA, ldsA);
        LDS_BARRIER();
    }
    // epilogue: B lags one step
    EW(accB, accfB, T_ - 1, lenB, cB, hB, outB, ldsB);

    h_out[(size_t)(row0 + g_own) * H_ + col16] = hA;
    c_out[(size_t)(row0 + g_own) * H_ + col16] = cA;
    h_out[(size_t)(row0 + 4 + g_own) * H_ + col16] = hB;
    c_out[(size_t)(row0 + 4 + g_own) * H_ + col16] = cB;
}

// ---------------- fallback LSTM (R7 structure, f32 x; proven algebra) ----------------
__launch_bounds__(512, 2)
__global__ void lstm_fb_kernel(const float* __restrict__ embedded,
                               const int* __restrict__ lengths,
                               const float* __restrict__ W_ih,
                               const float* __restrict__ W_hh,
                               const float* __restrict__ b_ih,
                               const float* __restrict__ b_hh,
                               float* __restrict__ outputs,
                               float* __restrict__ h_out,
                               float* __restrict__ c_out) {
    __shared__ __align__(16) char h_lds[2 * HBUF];
    const int tid  = threadIdx.x;
    const int lane = tid & 63;
    const int wave = tid >> 6;
    const int row0 = blockIdx.x * 4;
    const int col16  = (wave << 4) + (lane & 15);
    const int kgrp8  = (lane >> 4) * 8;
    const int kgrp16 = (lane >> 4) * 16;
    const int brow   = (lane & 15) >> 2;
    const int g_own  = lane >> 4;

    bf16x8 wx[4]; f32x4 biasv[4]; i32x4 wh[4][2]; float dq[4];
    #pragma unroll
    for (int gt = 0; gt < 4; gt++) {
        const float scale = (gt == 2) ? (2.0f * L2E) : L2E;
        const int gcol = gt * H_ + col16;
        {
            const float* p = W_ih + (size_t)gcol * E_ + kgrp8;
            bf16x8 v;
            #pragma unroll
            for (int j = 0; j < 8; j++) v[j] = f2bf(p[j] * scale);
            wx[gt] = v;
        }
        biasv[gt] = (f32x4)((b_ih[gcol] + b_hh[gcol]) * scale);
        const float* q = W_hh + (size_t)gcol * H_;
        float m = 0.0f;
        #pragma unroll
        for (int t2 = 0; t2 < 2; t2++)
            #pragma unroll
            for (int j = 0; j < 16; j++)
                m = fmaxf(m, fabsf(q[t2 * 64 + kgrp16 + j]));
        m = fmaxf(m, __shfl_xor(m, 16));
        m = fmaxf(m, __shfl_xor(m, 32));
        const float s = 127.0f / m;
        dq[gt] = scale * m * (1.0f / (127.0f * 127.0f));
        #pragma unroll
        for (int t2 = 0; t2 < 2; t2++) {
            i32x4 v;
            #pragma unroll
            for (int d = 0; d < 4; d++) {
                int word = 0;
                #pragma unroll
                for (int b2 = 0; b2 < 4; b2++) {
                    int qi = (int)rintf(q[t2 * 64 + kgrp16 + d * 4 + b2] * s);
                    word |= (qi & 0xFF) << (b2 * 8);
                }
                v[d] = word;
            }
            wh[gt][t2] = v;
        }
    }
    const int len = lengths[row0 + g_own];
    float cr = 0.0f, hr = 0.0f;
    const float* xp = embedded + ((size_t)(row0 + brow) * T_) * E_ + kgrp8;
    const int rbase = brow * HROW + kgrp16;
    const int wofs  = g_own * HROW + col16;
    float* const out_base = outputs + (size_t)(row0 + g_own) * T_ * H_ + col16;
    for (int i = tid; i < 2 * HBUF; i += 512) h_lds[i] = 0;
    __syncthreads();
    float4 xlo = *(const float4*)xp, xhi = *(const float4*)(xp + 4);
    int RD = 0;
    for (int t = 0; t < T_; ++t) {
        i32x4 ah0 = *(const i32x4*)&h_lds[RD + rbase];
        i32x4 ah1 = *(const i32x4*)&h_lds[RD + rbase + 64];
        bf16x8 xa = pack8(xlo, xhi);
        if (t + 1 < T_) {
            const float* xq = xp + (size_t)(t + 1) * E_;
            xlo = *(const float4*)xq; xhi = *(const float4*)(xq + 4);
        }
        f32x4 accf[4]; i32x4 acci[4];
        #pragma unroll
        for (int gt = 0; gt < 4; gt++)
            accf[gt] = __builtin_amdgcn_mfma_f32_16x16x32_bf16(xa, wx[gt], biasv[gt], 0, 0, 0);
        #pragma unroll
        for (int gt = 0; gt < 4; gt++)
            acci[gt] = __builtin_amdgcn_mfma_i32_16x16x64_i8(ah0, wh[gt][0], (i32x4)0, 0, 0, 0);
        #pragma unroll
        for (int gt = 0; gt < 4; gt++)
            acci[gt] = __builtin_amdgcn_mfma_i32_16x16x64_i8(ah1, wh[gt][1], acci[gt], 0, 0, 0);
        float a_i = fmaf((float)acci[0][0], dq[0], accf[0][0]);
        float a_f = fmaf((float)acci[1][0], dq[1], accf[1][0]);
        float a_g = fmaf((float)acci[2][0], dq[2], accf[2][0]);
        float a_o = fmaf((float)acci[3][0], dq[3], accf[3][0]);
        float Ai = exp2f(fminf(-a_i, CLM));
        float Af = exp2f(fminf(-a_f, CLM));
        float Eg = exp2f(fminf(a_g, CLM));
        float pAi = 1.0f + Ai, pAf = 1.0f + Af, pEg = Eg + 1.0f;
        float D = pAi * pEg;
        float R = __builtin_amdgcn_rcpf(D * pAf);
        float f_ = D * R;
        float ig = (Eg - 1.0f) * pAf * R;
        float c_new = fmaf(f_, cr, ig);
        float Ec = exp2f(fminf(c_new * (2.0f * L2E), CLM));
        float Ao = exp2f(fminf(-a_o, CLM));
        float Rh = __builtin_amdgcn_rcpf((1.0f + Ao) * (Ec + 1.0f));
        float h_new = (Ec - 1.0f) * Rh;
        bool m = (t < len);
        cr = m ? c_new : cr;
        hr = m ? h_new : hr;
        out_base[(size_t)t * H_] = m ? h_new : 0.0f;
        int qh = (int)rintf(hr * 127.0f);
        const int WR = RD ^ (2 * HBUF / 2);
        h_lds[WR + wofs] = (char)qh;
        RD = WR;
        LDS_BARRIER();
    }
    h_out[(size_t)(row0 + g_own) * H_ + col16] = hr;
    c_out[(size_t)(row0 + g_own) * H_ + col16] = cr;
}

extern "C" void kernel_launch(void* const* d_in, const int* in_sizes, int n_in,
                              void* d_out, int out_size, void* d_ws, size_t ws_size,
                              hipStream_t stream) {
    const int*   obs_ids       = (const int*)d_in[0];
    const int*   obs_slot      = (const int*)d_in[1];
    const int*   action_ids    = (const int*)d_in[2];
    const int*   is_action     = (const int*)d_in[3];
    const int*   input_lengths = (const int*)d_in[4];
    const float* action_emb    = (const float*)d_in[5];
    const float* obs_emb       = (const float*)d_in[6];
    const float* W_ih          = (const float*)d_in[7];
    const float* W_hh          = (const float*)d_in[8];
    const float* b_ih          = (const float*)d_in[9];
    const float* b_hh          = (const float*)d_in[10];

    float* out      = (float*)d_out;
    float* outputs  = out;                                   // [B,T,H]
    float* h_out    = out + (size_t)B_ * T_ * H_;            // [1,B,H]
    float* c_out    = h_out + (size_t)B_ * H_;               // [1,B,H]
    float* embedded = c_out + (size_t)B_ * H_;               // [B,T,E]

    const size_t xbf_bytes = (size_t)B_ * T_ * E_ * sizeof(unsigned short);
    const bool use_ap = (ws_size >= xbf_bytes);
    unsigned short* xbf = use_ap ? (unsigned short*)d_ws : nullptr;

    hipLaunchKernelGGL(embed_kernel, dim3((B_ * T_ + 255) / 256), dim3(256), 0, stream,
                       obs_ids, obs_slot, action_ids, is_action, action_emb, obs_emb,
                       embedded, xbf);

    if (use_ap) {
        hipLaunchKernelGGL(lstm_ap2_kernel, dim3(B_ / 8), dim3(512), 0, stream,
                           xbf, input_lengths, W_ih, W_hh, b_ih, b_hh,
                           outputs, h_out, c_out);
    } else {
        hipLaunchKernelGGL(lstm_fb_kernel, dim3(B_ / 4), dim3(512), 0, stream,
                           embedded, input_lengths, W_ih, W_hh, b_ih, b_hh,
                           outputs, h_out, c_out);
    }
}

// Round 10
// 487.289 us; speedup vs baseline: 1.9245x; 1.9245x over previous
//
#include <hip/hip_runtime.h>

#define B_ 256
#define T_ 1024
#define E_ 32
#define H_ 128
#define NOBS_ 1048576
#define L2E 1.4426950408889634f
#define CLM 30.0f

#define HROW 144              // bytes per h row in LDS (128 i8 + 16 pad)
#define HBUF (4 * HROW)       // one h buffer (4 rows)

typedef __attribute__((ext_vector_type(8))) short bf16x8;
typedef __attribute__((ext_vector_type(4))) float f32x4;
typedef __attribute__((ext_vector_type(4))) int   i32x4;

// LDS-only barrier: drains LDS ops only; global loads/stores stay in flight.
#define LDS_BARRIER() asm volatile("s_waitcnt lgkmcnt(0)\n\ts_barrier" ::: "memory")

__device__ __forceinline__ short f2bf(float x) {
    unsigned u = __float_as_uint(x);
    unsigned r = u + 0x7FFFu + ((u >> 16) & 1u);   // RNE
    return (short)(r >> 16);
}

__device__ __forceinline__ bf16x8 pack8(float4 lo, float4 hi) {
    int x0, x1, x2, x3;
    asm("v_cvt_pk_bf16_f32 %0, %1, %2" : "=v"(x0) : "v"(lo.x), "v"(lo.y));
    asm("v_cvt_pk_bf16_f32 %0, %1, %2" : "=v"(x1) : "v"(lo.z), "v"(lo.w));
    asm("v_cvt_pk_bf16_f32 %0, %1, %2" : "=v"(x2) : "v"(hi.x), "v"(hi.y));
    asm("v_cvt_pk_bf16_f32 %0, %1, %2" : "=v"(x3) : "v"(hi.z), "v"(hi.w));
    i32x4 xi; xi[0] = x0; xi[1] = x1; xi[2] = x2; xi[3] = x3;
    return __builtin_bit_cast(bf16x8, xi);
}

// ---------------- embedding kernel (proven) ----------------
__global__ void embed_kernel(const int* __restrict__ obs_ids,
                             const int* __restrict__ obs_slot,
                             const int* __restrict__ action_ids,
                             const int* __restrict__ is_action,
                             const float* __restrict__ action_emb,
                             const float* __restrict__ obs_emb,
                             float* __restrict__ embedded,
                             unsigned short* __restrict__ xbf) {
    __shared__ float s_act[5 * E_];
    __shared__ float s_obs[11 * E_];
    for (int i = threadIdx.x; i < 5 * E_; i += blockDim.x) s_act[i] = action_emb[i];
    for (int i = threadIdx.x; i < 11 * E_; i += blockDim.x) s_obs[i] = obs_emb[i];
    __syncthreads();

    int s = blockIdx.x * blockDim.x + threadIdx.x;
    if (s >= B_ * T_) return;

    float acc[E_];
    if (is_action[s]) {
        int a = action_ids[s];
        #pragma unroll
        for (int e = 0; e < E_; e++) acc[e] = s_act[a * E_ + e];
    } else {
        #pragma unroll
        for (int e = 0; e < E_; e++) acc[e] = 0.0f;
        int lo = 0, hi = NOBS_;
        while (lo < hi) {
            int mid = (lo + hi) >> 1;
            if (obs_slot[mid] < s) lo = mid + 1; else hi = mid;
        }
        int j = lo;
        while (j < NOBS_ && obs_slot[j] == s) {
            int id = obs_ids[j];
            #pragma unroll
            for (int e = 0; e < E_; e++) acc[e] += s_obs[id * E_ + e];
            j++;
        }
    }
    float4* dst = (float4*)(embedded + (size_t)s * E_);
    #pragma unroll
    for (int q = 0; q < E_ / 4; q++) {
        float4 v; v.x = acc[4*q]; v.y = acc[4*q+1]; v.z = acc[4*q+2]; v.w = acc[4*q+3];
        dst[q] = v;
    }
    if (xbf) {
        unsigned short tmp[E_];
        #pragma unroll
        for (int e = 0; e < E_; e++) tmp[e] = (unsigned short)f2bf(acc[e]);
        int4* d2 = (int4*)(xbf + (size_t)s * E_);
        #pragma unroll
        for (int q = 0; q < E_ / 8; q++) d2[q] = ((const int4*)tmp)[q];
    }
}

// ---------------- LSTM kernel (R7 structure + setprio/magic-quant/shared-rcp) ----------------
// 8 waves x RPB=4, one gate element per lane. h-part: i8 16x16x64 (exact i32
// acc, per-column W_hh scale). x-part accf(t+1) hoisted (issues after h-MFMAs,
// executes in matrix pipe during EW). setprio(1) wraps the MFMA cluster so an
// MFMA-phase wave outprioritizes its EW-phase SIMD partner (T5 skew).
template<bool BF16X>
__launch_bounds__(512, 2)
__global__ void lstm_kernel(const float* __restrict__ embedded,
                            const unsigned short* __restrict__ xbf,
                            const int* __restrict__ lengths,
                            const float* __restrict__ W_ih,
                            const float* __restrict__ W_hh,
                            const float* __restrict__ b_ih,
                            const float* __restrict__ b_hh,
                            float* __restrict__ outputs,
                            float* __restrict__ h_out,
                            float* __restrict__ c_out) {
    __shared__ __align__(16) char h_lds[2 * HBUF];   // double-buffered [4][HROW] i8

    const int tid  = threadIdx.x;
    const int lane = tid & 63;
    const int wave = tid >> 6;
    const int row0 = blockIdx.x * 4;

    const int col16  = (wave << 4) + (lane & 15);
    const int kgrp8  = (lane >> 4) * 8;
    const int kgrp16 = (lane >> 4) * 16;
    const int brow   = (lane & 15) >> 2;           // A-row (dup x4) — proven layout
    const int g_own  = lane >> 4;                  // batch row this lane OWNS

    // ---- weights: x-part bf16 (log2e-scaled; 2x for g), h-part i8 ----
    bf16x8 wx[4]; f32x4 biasv[4]; i32x4 wh[4][2]; float dq[4];
    #pragma unroll
    for (int gt = 0; gt < 4; gt++) {
        const float scale = (gt == 2) ? (2.0f * L2E) : L2E;
        const int gcol = gt * H_ + col16;
        {
            const float* p = W_ih + (size_t)gcol * E_ + kgrp8;
            bf16x8 v;
            #pragma unroll
            for (int j = 0; j < 8; j++) v[j] = f2bf(p[j] * scale);
            wx[gt] = v;
        }
        biasv[gt] = (f32x4)((b_ih[gcol] + b_hh[gcol]) * scale);

        const float* q = W_hh + (size_t)gcol * H_;
        float m = 0.0f;
        #pragma unroll
        for (int t2 = 0; t2 < 2; t2++)
            #pragma unroll
            for (int j = 0; j < 16; j++)
                m = fmaxf(m, fabsf(q[t2 * 64 + kgrp16 + j]));
        m = fmaxf(m, __shfl_xor(m, 16));
        m = fmaxf(m, __shfl_xor(m, 32));
        const float s = 127.0f / m;
        dq[gt] = scale * m * (1.0f / (127.0f * 127.0f));
        #pragma unroll
        for (int t2 = 0; t2 < 2; t2++) {
            i32x4 v;
            #pragma unroll
            for (int d = 0; d < 4; d++) {
                int word = 0;
                #pragma unroll
                for (int b2 = 0; b2 < 4; b2++) {
                    int qi = (int)rintf(q[t2 * 64 + kgrp16 + d * 4 + b2] * s);
                    word |= (qi & 0xFF) << (b2 * 8);
                }
                v[d] = word;
            }
            wh[gt][t2] = v;
        }
    }

    const int len = lengths[row0 + g_own];
    float cr = 0.0f, hr = 0.0f;

    const unsigned short* xpb = xbf + ((size_t)(row0 + brow) * T_) * E_ + kgrp8;
    const float*          xpf = embedded + ((size_t)(row0 + brow) * T_) * E_ + kgrp8;

    const int rbase = brow * HROW + kgrp16;
    const int wofs  = g_own * HROW + col16;
    float* const out_base = outputs + (size_t)(row0 + g_own) * T_ * H_ + col16;

    for (int i = tid; i < 2 * HBUF; i += 512) h_lds[i] = 0;
    __syncthreads();

    int4 xfA, xfB;
    float4 flA, fhA, flB, fhB;
    auto loadx = [&](int t, int4& xi4, float4& fl, float4& fh) {
        if (BF16X) {
            xi4 = *(const int4*)(xpb + (size_t)t * E_);
        } else {
            fl = *(const float4*)(xpf + (size_t)t * E_);
            fh = *(const float4*)(xpf + (size_t)t * E_ + 4);
        }
    };
    auto mkfrag = [&](const int4& xi4, const float4& fl, const float4& fh) -> bf16x8 {
        if (BF16X) return __builtin_bit_cast(bf16x8, xi4);
        return pack8(fl, fh);
    };

    // prologue: x(0), x(1); accfA = bias + x(0)*W_ih
    loadx(0, xfA, flA, fhA);
    loadx(1, xfB, flB, fhB);
    f32x4 accfA[4], accfB[4];
    {
        bf16x8 xa = mkfrag(xfA, flA, fhA);
        #pragma unroll
        for (int gt = 0; gt < 4; gt++)
            accfA[gt] = __builtin_amdgcn_mfma_f32_16x16x32_bf16(xa, wx[gt], biasv[gt], 0, 0, 0);
    }

    auto step = [&](int t, int RD, int WR,
                    f32x4* accf_cur, f32x4* accf_nxt,
                    const int4& xf_nx, const float4& fl_nx, const float4& fh_nx,
                    int4& xf_pf, float4& fl_pf, float4& fh_pf,
                    bool PF1, bool PF2) {
        // h A-fragments (i8), 2 K-tiles of 64
        i32x4 ah0 = *(const i32x4*)&h_lds[RD + rbase];
        i32x4 ah1 = *(const i32x4*)&h_lds[RD + rbase + 64];

        // prefetch x(t+2) early (in flight across the barrier)
        if (PF2) loadx(t + 2, xf_pf, fl_pf, fh_pf);

        // ---- MFMA cluster (priority-boosted: saturate matrix pipe while the
        // other wave on this SIMD runs its EW VALU phase) ----
        __builtin_amdgcn_s_setprio(1);
        i32x4 acci[4];
        #pragma unroll
        for (int gt = 0; gt < 4; gt++)
            acci[gt] = __builtin_amdgcn_mfma_i32_16x16x64_i8(ah0, wh[gt][0], (i32x4)0, 0, 0, 0);
        #pragma unroll
        for (int gt = 0; gt < 4; gt++)
            acci[gt] = __builtin_amdgcn_mfma_i32_16x16x64_i8(ah1, wh[gt][1], acci[gt], 0, 0, 0);
        if (PF1) {  // hoisted x-part for t+1: runs in matrix pipe during EW
            bf16x8 xa = mkfrag(xf_nx, fl_nx, fh_nx);
            #pragma unroll
            for (int gt = 0; gt < 4; gt++)
                accf_nxt[gt] = __builtin_amdgcn_mfma_f32_16x16x32_bf16(xa, wx[gt], biasv[gt], 0, 0, 0);
        }
        __builtin_amdgcn_s_setprio(0);

        // ---- EW: shared-rcp (5 exp2 + 2 rcp; verified R9) ----
        float a_i = fmaf((float)acci[0][0], dq[0], accf_cur[0][0]);
        float a_f = fmaf((float)acci[1][0], dq[1], accf_cur[1][0]);
        float a_g = fmaf((float)acci[2][0], dq[2], accf_cur[2][0]);
        float a_o = fmaf((float)acci[3][0], dq[3], accf_cur[3][0]);
        float Ai = exp2f(fminf(-a_i, CLM));
        float Af = exp2f(fminf(-a_f, CLM));
        float Eg = exp2f(fminf(a_g, CLM));
        float pAi = 1.0f + Ai, pAf = 1.0f + Af, pEg = Eg + 1.0f;
        float D  = pAi * pEg;
        float R  = __builtin_amdgcn_rcpf(D * pAf);
        float f_ = D * R;                         // sigmoid(a_f)
        float ig = (Eg - 1.0f) * pAf * R;         // sigmoid(a_i)*tanh(g)
        float c_new = fmaf(f_, cr, ig);
        float Ec = exp2f(fminf(c_new * (2.0f * L2E), CLM));
        float Ao = exp2f(fminf(-a_o, CLM));
        float Rh = __builtin_amdgcn_rcpf((1.0f + Ao) * (Ec + 1.0f));
        float h_new = (Ec - 1.0f) * Rh;           // sigmoid(a_o)*tanh(c)
        bool m = (t < len);
        cr = m ? c_new : cr;
        hr = m ? h_new : hr;

        // h write-back first (critical path for next step), magic-fma RNE quant
        unsigned qb = __float_as_uint(fmaf(hr, 127.0f, 12582912.0f));
        h_lds[WR + wofs] = (char)qb;
        out_base[(size_t)t * H_] = m ? h_new : 0.0f;   // fire-and-forget

        LDS_BARRIER();
    };

    for (int t = 0; t < T_ - 2; t += 2) {
        step(t,     0,    HBUF, accfA, accfB, xfB, flB, fhB, xfA, flA, fhA, true, true);
        step(t + 1, HBUF, 0,    accfB, accfA, xfA, flA, fhA, xfB, flB, fhB, true, t + 3 < T_);
    }
    step(T_ - 2, 0,    HBUF, accfA, accfB, xfB, flB, fhB, xfA, flA, fhA, true,  false);
    step(T_ - 1, HBUF, 0,    accfB, accfA, xfA, flA, fhA, xfB, flB, fhB, false, false);

    h_out[(size_t)(row0 + g_own) * H_ + col16] = hr;
    c_out[(size_t)(row0 + g_own) * H_ + col16] = cr;
}

extern "C" void kernel_launch(void* const* d_in, const int* in_sizes, int n_in,
                              void* d_out, int out_size, void* d_ws, size_t ws_size,
                              hipStream_t stream) {
    const int*   obs_ids       = (const int*)d_in[0];
    const int*   obs_slot      = (const int*)d_in[1];
    const int*   action_ids    = (const int*)d_in[2];
    const int*   is_action     = (const int*)d_in[3];
    const int*   input_lengths = (const int*)d_in[4];
    const float* action_emb    = (const float*)d_in[5];
    const float* obs_emb       = (const float*)d_in[6];
    const float* W_ih          = (const float*)d_in[7];
    const float* W_hh          = (const float*)d_in[8];
    const float* b_ih          = (const float*)d_in[9];
    const float* b_hh          = (const float*)d_in[10];

    float* out      = (float*)d_out;
    float* outputs  = out;                                   // [B,T,H]
    float* h_out    = out + (size_t)B_ * T_ * H_;            // [1,B,H]
    float* c_out    = h_out + (size_t)B_ * H_;               // [1,B,H]
    float* embedded = c_out + (size_t)B_ * H_;               // [B,T,E]

    const size_t xbf_bytes = (size_t)B_ * T_ * E_ * sizeof(unsigned short);
    const bool use_bf16x = (ws_size >= xbf_bytes);
    unsigned short* xbf = use_bf16x ? (unsigned short*)d_ws : nullptr;

    hipLaunchKernelGGL(embed_kernel, dim3((B_ * T_ + 255) / 256), dim3(256), 0, stream,
                       obs_ids, obs_slot, action_ids, is_action, action_emb, obs_emb,
                       embedded, xbf);

    if (use_bf16x) {
        hipLaunchKernelGGL((lstm_kernel<true>), dim3(B_ / 4), dim3(512), 0, stream,
                           embedded, xbf, input_lengths, W_ih, W_hh, b_ih, b_hh,
                           outputs, h_out, c_out);
    } else {
        hipLaunchKernelGGL((lstm_kernel<false>), dim3(B_ / 4), dim3(512), 0, stream,
                           embedded, xbf, input_lengths, W_ih, W_hh, b_ih, b_hh,
                           outputs, h_out, c_out);
    }
}